// Round 7
// baseline (310.890 us; speedup 1.0000x reference)
//
#include <hip/hip_runtime.h>
#include <math.h>

#define B_ 4
#define N_ 4096
#define BN_ (B_*N_)
#define JCHUNKS 4
#define JCLEN (N_/JCHUNKS)   // 1024
#define TJ 64
#define STEPS (JCLEN/TJ)     // 16

typedef __bf16 v8bf __attribute__((ext_vector_type(8)));
typedef unsigned short u16x8 __attribute__((ext_vector_type(8)));
typedef float v4f __attribute__((ext_vector_type(4)));

#define LOG2E 1.44269504088896340736f
#define AEXP 8388608.0f                  /* 2^23 */
#define CBF  1065353216.0f               /* (float)(127<<23), exact in f32 */
#define FSLA_K (LOG2E*AEXP)              /* fs -> fixed-point log2 exponent scale */
#define CPROX_A (-50.0f*LOG2E*AEXP)      /* prox: -d/(2*sigma^2) in fixed-point log2 */
#define INVSQRT3 0.57735026918962576f
/* smoothstep sigmoid approx: sigmoid(5(s-tau)) ~ S((s-tau)/1.4 + 0.5) */
#define GS (1.0f/1.4f)
#define GC_FLOW  (0.5f - 0.8f*GS)
#define GC_COLOR (0.5f - 0.7f*GS)
#define GC_PROX  (0.5f - 0.5f*GS)

__device__ __forceinline__ float fsqrt(float x){ return __builtin_amdgcn_sqrtf(x); }

/* gate as a MACRO: direct lvalue accumulator updates — no address-taking,
   keeps the 24 accumulators in registers (R6 lesson: float& params -> scratch) */
#define GATE(s_, gc_, spA, smA)                                                   \
  { float t_  = __builtin_fminf(__builtin_fmaxf(fmaf((s_), GS, (gc_)), 0.f), 1.f);\
    float gp_ = t_*t_*fmaf(t_, -2.f, 3.f);                                        \
    spA += __builtin_bit_cast(float, (int)fmaf(gp_, fslA, CBF));                  \
    smA += __builtin_bit_cast(float, (int)fmaf(gp_, fslA, cb2f)); }

// ---------------- prep: normalize features -> bf16, per-point scalars ----------------
extern "C" __global__ __launch_bounds__(256) void prep_k(
    const float* __restrict__ flow, const float* __restrict__ color,
    const float* __restrict__ coord, const float* __restrict__ feat,
    unsigned short* __restrict__ fn, float* __restrict__ scal)
{
  const int wave = blockIdx.x*4 + (threadIdx.x>>6);
  const int lane = threadIdx.x & 63;
  float v = feat[(size_t)wave*64 + lane];
  float ss = v*v;
  #pragma unroll
  for (int d=32; d; d>>=1) ss += __shfl_xor(ss, d);
  float sc = 1.0f/(sqrtf(ss)+1e-7f);     // matches ref: f/(||f||+1e-7)
  float x = v*sc;
  unsigned u = __builtin_bit_cast(unsigned, x);
  unsigned r = (u + 0x7fffu + ((u>>16)&1u)) >> 16;   // RN-even f32->bf16
  fn[(size_t)wave*64+lane] = (unsigned short)r;
  if (lane==0) {
    float fx=flow[wave*3+0], fy=flow[wave*3+1], fz=flow[wave*3+2];
    float rn = 1.0f/sqrtf(fx*fx+fy*fy+fz*fz + 1e-8f);
    const float k = 1.0f/255.0f;
    float cx=color[wave*3+0]*k, cy=color[wave*3+1]*k, cz=color[wave*3+2]*k;
    float px=coord[wave*3+0], py=coord[wave*3+1], pz=coord[wave*3+2];
    float* o = scal + (size_t)wave*12;
    o[0]=fx*rn; o[1]=fy*rn; o[2]=fz*rn;
    o[3]=cx; o[4]=cy; o[5]=cz;
    o[6]=cx*cx+cy*cy+cz*cz;
    o[7]=px; o[8]=py; o[9]=pz;
    o[10]=px*px+py*py+pz*pz;
    o[11]=0.f;
  }
}

// ---------------- main: pairwise tiles ----------------
extern "C" __global__ __launch_bounds__(256,3) void main_k(
    const unsigned short* __restrict__ fn, const float* __restrict__ scal,
    float* __restrict__ part)
{
  __shared__ unsigned short fnj[TJ*64];  // 8 KB, XOR-swizzled rows (128B each)
  __shared__ float scj[TJ*12];           // 3 KB

  const int bid = blockIdx.x;
  const int jc    = bid & (JCHUNKS-1);
  const int t     = bid >> 2;
  const int b     = t >> 6;
  const int itile = t & 63;
  const int tid  = threadIdx.x;
  const int w    = tid >> 6;
  const int lane = tid & 63;
  const int g    = lane >> 4;
  const int col  = lane & 15;
  const int irow0 = itile*64 + w*16;

  const unsigned short* fnb = fn + (size_t)b*N_*64;
  const float* scb = scal + (size_t)b*N_*12;

  // A fragments: row = lane&15, k = (lane>>4)*8 + e  (two K=32 halves), held in regs
  const int arow = irow0 + col;
  v8bf a0 = __builtin_bit_cast(v8bf, *(const u16x8*)(fnb + (size_t)arow*64 + g*8));
  v8bf a1 = __builtin_bit_cast(v8bf, *(const u16x8*)(fnb + (size_t)arow*64 + 32 + g*8));

  // i-side scalars for this lane's 4 output rows (row = g*4 + r)
  float fhi[4][3], n2c[4][3], n2p[4][3], csqi[4], psqi[4];
  #pragma unroll
  for (int r=0;r<4;++r) {
    const float* s = scb + (size_t)(irow0 + g*4 + r)*12;
    v4f s0 = *(const v4f*)(s), s1 = *(const v4f*)(s+4), s2 = *(const v4f*)(s+8);
    fhi[r][0]=s0.x; fhi[r][1]=s0.y; fhi[r][2]=s0.z;
    n2c[r][0]=-2.f*s0.w; n2c[r][1]=-2.f*s1.x; n2c[r][2]=-2.f*s1.y;
    csqi[r]=s1.z;
    n2p[r][0]=-2.f*s1.w; n2p[r][1]=-2.f*s2.x; n2p[r][2]=-2.f*s2.y;
    psqi[r]=s2.z;
  }

  // six accumulator banks, only constant (unrolled) indices touch them
  float spf[4], smf[4], spc[4], smc[4], spp[4], smp[4];
  #pragma unroll
  for (int r=0;r<4;++r){ spf[r]=0.f; smf[r]=0.f; spc[r]=0.f; smc[r]=0.f; spp[r]=0.f; smp[r]=0.f; }

  const unsigned short* fng = fnb + (size_t)(jc*JCLEN)*64;
  const float* scg = scb + (size_t)(jc*JCLEN)*12;

  for (int step=0; step<STEPS; ++step) {
    __syncthreads();
    #pragma unroll
    for (int q=0;q<2;++q) {               // stage 64 rows x 128B of fn, swizzled
      int idx = tid + q*256;
      int row = idx>>3, seg = idx&7;
      const float4 src = *(const float4*)(fng + (size_t)(step*64+row)*64 + seg*8);
      *(float4*)((char*)fnj + row*128 + ((seg*16) ^ ((row&7)<<4))) = src;
    }
    if (tid < 192) {                      // stage 64 rows x 48B of scalars
      int row = tid/3, seg = tid - row*3;
      *(float4*)(scj + row*12 + seg*4) = *(const float4*)(scg + (size_t)(step*64+row)*12 + seg*4);
    }
    __syncthreads();

    #pragma unroll
    for (int sub=0; sub<4; ++sub) {
      const int jloc = sub*16 + col;
      const int sw = (jloc&7)<<4;
      const char* rowp = (const char*)fnj + jloc*128;
      v8bf b0 = __builtin_bit_cast(v8bf, *(const u16x8*)(rowp + ((g*16) ^ sw)));
      v8bf b1 = __builtin_bit_cast(v8bf, *(const u16x8*)(rowp + ((64 + g*16) ^ sw)));
      v4f j0 = *(const v4f*)(scj + jloc*12);
      v4f j1 = *(const v4f*)(scj + jloc*12 + 4);
      v4f j2 = *(const v4f*)(scj + jloc*12 + 8);

      v4f acc = {0.f,0.f,0.f,0.f};
      acc = __builtin_amdgcn_mfma_f32_16x16x32_bf16(a0, b0, acc, 0,0,0);
      acc = __builtin_amdgcn_mfma_f32_16x16x32_bf16(a1, b1, acc, 0,0,0);

      #pragma unroll
      for (int r=0;r<4;++r) {
        const float fs   = acc[r];          // feature cosine (i=g*4+r, j=jloc)
        const float fslA = fs * FSLA_K;     // log2-domain fixed-point exponent scale
        const float cb2f = CBF - fslA;
        const float sf = fhi[r][0]*j0.x + fhi[r][1]*j0.y + fhi[r][2]*j0.z;  // flow cos
        float d2c = csqi[r] + j1.z;
        d2c = fmaf(n2c[r][0], j0.w, d2c);
        d2c = fmaf(n2c[r][1], j1.x, d2c);
        d2c = fmaf(n2c[r][2], j1.y, d2c);
        const float scl = fmaf(fsqrt(fmaxf(d2c,0.f)), -INVSQRT3, 1.0f);     // color sim
        float d2p = psqi[r] + j2.z;
        d2p = fmaf(n2p[r][0], j1.w, d2p);
        d2p = fmaf(n2p[r][1], j2.x, d2p);
        d2p = fmaf(n2p[r][2], j2.y, d2p);
        // prox sim via Schraudolph exp2 (clamped: huge negative exponent -> ~0)
        float pb = fmaf(fsqrt(fmaxf(d2p,0.f)), CPROX_A, CBF);
        const float spr = __builtin_bit_cast(float, (int)__builtin_fmaxf(pb, 0.f));
        GATE(sf,  GC_FLOW,  spf[r], smf[r]);
        GATE(scl, GC_COLOR, spc[r], smc[r]);
        GATE(spr, GC_PROX,  spp[r], smp[r]);
      }
    }
  }

  // reduce cols 0..15 (16-lane groups hold one row's 16 j-columns)
  #pragma unroll
  for (int r=0;r<4;++r) {
    float v0=spf[r], v1=smf[r], v2=spc[r], v3=smc[r], v4=spp[r], v5=smp[r];
    #pragma unroll
    for (int d=1; d<16; d<<=1) {
      v0 += __shfl_xor(v0,d); v1 += __shfl_xor(v1,d); v2 += __shfl_xor(v2,d);
      v3 += __shfl_xor(v3,d); v4 += __shfl_xor(v4,d); v5 += __shfl_xor(v5,d);
    }
    if (col==0) {
      // jc-major layout: each block writes a contiguous 1.5KB region
      float* o = part + ((size_t)jc*BN_ + (size_t)b*N_ + irow0 + g*4 + r)*6;
      o[0]=v0; o[1]=v1; o[2]=v2; o[3]=v3; o[4]=v4; o[5]=v5;
    }
  }
}

// ---------------- finalize: log1p + mean, two stages ----------------
extern "C" __global__ __launch_bounds__(256) void fin1_k(
    const float* __restrict__ part, float* __restrict__ partial)
{
  const int pt = blockIdx.x*256 + threadIdx.x;
  float s[6] = {0.f,0.f,0.f,0.f,0.f,0.f};
  #pragma unroll
  for (int jcc=0;jcc<JCHUNKS;++jcc) {
    const float* pp = part + ((size_t)jcc*BN_ + pt)*6;
    #pragma unroll
    for (int k=0;k<6;++k) s[k] += pp[k];
  }
  float acc = log1pf(s[0]) + log1pf(s[1]) + log1pf(s[2])
            + log1pf(s[3]) + log1pf(s[4]) + log1pf(s[5]);
  #pragma unroll
  for (int d=32; d; d>>=1) acc += __shfl_xor(acc, d);
  __shared__ float wsum[4];
  if ((threadIdx.x&63)==0) wsum[threadIdx.x>>6] = acc;
  __syncthreads();
  if (threadIdx.x==0) partial[blockIdx.x] = wsum[0]+wsum[1]+wsum[2]+wsum[3];
}

extern "C" __global__ void fin2_k(const float* __restrict__ partial, float* __restrict__ out)
{
  float acc = partial[threadIdx.x];   // 64 threads
  #pragma unroll
  for (int d=32; d; d>>=1) acc += __shfl_xor(acc, d);
  if (threadIdx.x==0) out[0] = -acc * (1.0f/(float)BN_);
}

extern "C" void kernel_launch(void* const* d_in, const int* in_sizes, int n_in,
                              void* d_out, int out_size, void* d_ws, size_t ws_size,
                              hipStream_t stream)
{
  const float* flow  = (const float*)d_in[0];
  const float* color = (const float*)d_in[1];
  const float* coord = (const float*)d_in[2];
  const float* feat  = (const float*)d_in[3];
  unsigned short* fn = (unsigned short*)d_ws;                                   // 2 MB
  float* scal = (float*)((char*)d_ws + (size_t)BN_*64*2);                       // 768 KB
  float* part = (float*)((char*)d_ws + (size_t)BN_*64*2 + (size_t)BN_*12*4);    // 1.5 MB
  float* partial = part + (size_t)BN_*JCHUNKS*6;                                // 256 B
  float* outp = (float*)d_out;
  hipLaunchKernelGGL(prep_k, dim3(BN_/4), dim3(256), 0, stream,
                     flow, color, coord, feat, fn, scal);
  hipLaunchKernelGGL(main_k, dim3(B_*(N_/64)*JCHUNKS), dim3(256), 0, stream,
                     fn, scal, part);
  hipLaunchKernelGGL(fin1_k, dim3(BN_/256), dim3(256), 0, stream, part, partial);
  hipLaunchKernelGGL(fin2_k, dim3(1), dim3(64), 0, stream, partial, outp);
}

// Round 8
// 119.610 us; speedup vs baseline: 2.5992x; 2.5992x over previous
//
#include <hip/hip_runtime.h>
#include <math.h>

#define B_ 4
#define N_ 4096
#define BN_ (B_*N_)
#define JCHUNKS 4
#define JCLEN (N_/JCHUNKS)   // 1024
#define TJ 64
#define STEPS (JCLEN/TJ)     // 16

typedef __bf16 v8bf __attribute__((ext_vector_type(8)));
typedef unsigned short u16x8 __attribute__((ext_vector_type(8)));
typedef float v4f __attribute__((ext_vector_type(4)));

#define LOG2E 1.44269504088896340736f
#define CPROX (-50.0f*LOG2E)            /* -1/(2*sigma^2) * log2(e) */
#define INVSQRT3 0.57735026918962576f
/* smoothstep sigmoid approx: sigmoid(5(s-tau)) ~ S((s-tau)/1.4 + 0.5) */
#define GS (1.0f/1.4f)
#define GC_FLOW  (0.5f - 0.8f*GS)
#define GC_COLOR (0.5f - 0.7f*GS)
#define GC_PROX  (0.5f - 0.5f*GS)

__device__ __forceinline__ float fexp2(float x){ return __builtin_amdgcn_exp2f(x); }
__device__ __forceinline__ float fsqrt(float x){ return __builtin_amdgcn_sqrtf(x); }

// ---------------- prep: normalize features -> bf16, per-point scalars ----------------
extern "C" __global__ __launch_bounds__(256) void prep_k(
    const float* __restrict__ flow, const float* __restrict__ color,
    const float* __restrict__ coord, const float* __restrict__ feat,
    unsigned short* __restrict__ fn, float* __restrict__ scal)
{
  const int wave = blockIdx.x*4 + (threadIdx.x>>6);
  const int lane = threadIdx.x & 63;
  float v = feat[(size_t)wave*64 + lane];
  float ss = v*v;
  #pragma unroll
  for (int d=32; d; d>>=1) ss += __shfl_xor(ss, d);
  float sc = 1.0f/(sqrtf(ss)+1e-7f);     // matches ref: f/(||f||+1e-7)
  float x = v*sc;
  unsigned u = __builtin_bit_cast(unsigned, x);
  unsigned r = (u + 0x7fffu + ((u>>16)&1u)) >> 16;   // RN-even f32->bf16
  fn[(size_t)wave*64+lane] = (unsigned short)r;
  if (lane==0) {
    float fx=flow[wave*3+0], fy=flow[wave*3+1], fz=flow[wave*3+2];
    float rn = 1.0f/sqrtf(fx*fx+fy*fy+fz*fz + 1e-8f);
    const float k = 1.0f/255.0f;
    float cx=color[wave*3+0]*k, cy=color[wave*3+1]*k, cz=color[wave*3+2]*k;
    float px=coord[wave*3+0], py=coord[wave*3+1], pz=coord[wave*3+2];
    float* o = scal + (size_t)wave*12;
    o[0]=fx*rn; o[1]=fy*rn; o[2]=fz*rn;
    o[3]=cx; o[4]=cy; o[5]=cz;
    o[6]=cx*cx+cy*cy+cz*cz;
    o[7]=px; o[8]=py; o[9]=pz;
    o[10]=px*px+py*py+pz*pz;
    o[11]=0.f;
  }
}

// ---------------- main: pairwise tiles (R2 base + smoothstep gates) ----------------
extern "C" __global__ __launch_bounds__(256,3) void main_k(
    const unsigned short* __restrict__ fn, const float* __restrict__ scal,
    float* __restrict__ part)
{
  __shared__ unsigned short fnj[TJ*64];  // 8 KB, XOR-swizzled rows (128B each)
  __shared__ float scj[TJ*12];           // 3 KB

  const int bid = blockIdx.x;
  const int jc    = bid & (JCHUNKS-1);
  const int t     = bid >> 2;
  const int b     = t >> 6;
  const int itile = t & 63;
  const int tid  = threadIdx.x;
  const int w    = tid >> 6;
  const int lane = tid & 63;
  const int g    = lane >> 4;
  const int col  = lane & 15;
  const int irow0 = itile*64 + w*16;

  const unsigned short* fnb = fn + (size_t)b*N_*64;
  const float* scb = scal + (size_t)b*N_*12;

  // A fragments: row = lane&15, k = (lane>>4)*8 + e  (two K=32 halves), held in regs
  const int arow = irow0 + col;
  v8bf a0 = __builtin_bit_cast(v8bf, *(const u16x8*)(fnb + (size_t)arow*64 + g*8));
  v8bf a1 = __builtin_bit_cast(v8bf, *(const u16x8*)(fnb + (size_t)arow*64 + 32 + g*8));

  // i-side scalars for this lane's 4 output rows (row = g*4 + r)
  float fhi[4][3], n2c[4][3], n2p[4][3], csqi[4], psqi[4];
  #pragma unroll
  for (int r=0;r<4;++r) {
    const float* s = scb + (size_t)(irow0 + g*4 + r)*12;
    v4f s0 = *(const v4f*)(s), s1 = *(const v4f*)(s+4), s2 = *(const v4f*)(s+8);
    fhi[r][0]=s0.x; fhi[r][1]=s0.y; fhi[r][2]=s0.z;
    n2c[r][0]=-2.f*s0.w; n2c[r][1]=-2.f*s1.x; n2c[r][2]=-2.f*s1.y;
    csqi[r]=s1.z;
    n2p[r][0]=-2.f*s1.w; n2p[r][1]=-2.f*s2.x; n2p[r][2]=-2.f*s2.y;
    psqi[r]=s2.z;
  }

  float spa[3][4], sma[3][4];
  #pragma unroll
  for (int l=0;l<3;++l)
    #pragma unroll
    for (int r=0;r<4;++r){ spa[l][r]=0.f; sma[l][r]=0.f; }

  const unsigned short* fng = fnb + (size_t)(jc*JCLEN)*64;
  const float* scg = scb + (size_t)(jc*JCLEN)*12;

  for (int step=0; step<STEPS; ++step) {
    __syncthreads();
    #pragma unroll
    for (int q=0;q<2;++q) {               // stage 64 rows x 128B of fn, swizzled
      int idx = tid + q*256;
      int row = idx>>3, seg = idx&7;
      const float4 src = *(const float4*)(fng + (size_t)(step*64+row)*64 + seg*8);
      *(float4*)((char*)fnj + row*128 + ((seg*16) ^ ((row&7)<<4))) = src;
    }
    if (tid < 192) {                      // stage 64 rows x 48B of scalars
      int row = tid/3, seg = tid - row*3;
      *(float4*)(scj + row*12 + seg*4) = *(const float4*)(scg + (size_t)(step*64+row)*12 + seg*4);
    }
    __syncthreads();

    #pragma unroll
    for (int sub=0; sub<4; ++sub) {
      const int jloc = sub*16 + col;
      const int sw = (jloc&7)<<4;
      const char* rowp = (const char*)fnj + jloc*128;
      v8bf b0 = __builtin_bit_cast(v8bf, *(const u16x8*)(rowp + ((g*16) ^ sw)));
      v8bf b1 = __builtin_bit_cast(v8bf, *(const u16x8*)(rowp + ((64 + g*16) ^ sw)));
      v4f j0 = *(const v4f*)(scj + jloc*12);
      v4f j1 = *(const v4f*)(scj + jloc*12 + 4);
      v4f j2 = *(const v4f*)(scj + jloc*12 + 8);

      v4f acc = {0.f,0.f,0.f,0.f};
      acc = __builtin_amdgcn_mfma_f32_16x16x32_bf16(a0, b0, acc, 0,0,0);
      acc = __builtin_amdgcn_mfma_f32_16x16x32_bf16(a1, b1, acc, 0,0,0);

      #pragma unroll
      for (int r=0;r<4;++r) {
        const float fs = acc[r];                    // feature cosine (i=g*4+r, j=jloc)
        const float sf = fhi[r][0]*j0.x + fhi[r][1]*j0.y + fhi[r][2]*j0.z;  // flow cos
        float d2c = csqi[r] + j1.z;
        d2c = fmaf(n2c[r][0], j0.w, d2c);
        d2c = fmaf(n2c[r][1], j1.x, d2c);
        d2c = fmaf(n2c[r][2], j1.y, d2c);
        const float scl = fmaf(fsqrt(fmaxf(d2c,0.f)), -INVSQRT3, 1.0f);      // color sim
        float d2p = psqi[r] + j2.z;
        d2p = fmaf(n2p[r][0], j1.w, d2p);
        d2p = fmaf(n2p[r][1], j2.x, d2p);
        d2p = fmaf(n2p[r][2], j2.y, d2p);
        const float spr = fexp2(fsqrt(fmaxf(d2p,0.f)) * CPROX);              // prox sim
        const float fsl = fs * LOG2E;
        const float E2 = fexp2(-fsl);               // exp(-fs), shared by 3 losses
        {
          float tt = __builtin_fminf(__builtin_fmaxf(fmaf(sf, GS, GC_FLOW), 0.f), 1.f);
          float gp = tt*tt*fmaf(tt, -2.f, 3.f);     // ~sigmoid(5(s-tau))
          float e1 = fexp2(fsl*gp);                 // exp(fs*g+)
          spa[0][r] += e1; sma[0][r] += E2*e1;      // exp(-fs*g-) = E2*e1
        }
        {
          float tt = __builtin_fminf(__builtin_fmaxf(fmaf(scl, GS, GC_COLOR), 0.f), 1.f);
          float gp = tt*tt*fmaf(tt, -2.f, 3.f);
          float e1 = fexp2(fsl*gp);
          spa[1][r] += e1; sma[1][r] += E2*e1;
        }
        {
          float tt = __builtin_fminf(__builtin_fmaxf(fmaf(spr, GS, GC_PROX), 0.f), 1.f);
          float gp = tt*tt*fmaf(tt, -2.f, 3.f);
          float e1 = fexp2(fsl*gp);
          spa[2][r] += e1; sma[2][r] += E2*e1;
        }
      }
    }
  }

  // reduce cols 0..15 (16-lane groups hold one row's 16 j-columns)
  #pragma unroll
  for (int l=0;l<3;++l)
    #pragma unroll
    for (int r=0;r<4;++r) {
      float a=spa[l][r], c=sma[l][r];
      #pragma unroll
      for (int d=1; d<16; d<<=1){ a += __shfl_xor(a,d); c += __shfl_xor(c,d); }
      spa[l][r]=a; sma[l][r]=c;
    }
  if (col==0) {
    #pragma unroll
    for (int r=0;r<4;++r) {
      float* o = part + ((size_t)jc*BN_ + (size_t)b*N_ + irow0 + g*4 + r)*6;
      o[0]=spa[0][r]; o[1]=sma[0][r];
      o[2]=spa[1][r]; o[3]=sma[1][r];
      o[4]=spa[2][r]; o[5]=sma[2][r];
    }
  }
}

// ---------------- finalize: log1p + mean, two stages ----------------
extern "C" __global__ __launch_bounds__(256) void fin1_k(
    const float* __restrict__ part, float* __restrict__ partial)
{
  const int pt = blockIdx.x*256 + threadIdx.x;
  float s[6] = {0.f,0.f,0.f,0.f,0.f,0.f};
  #pragma unroll
  for (int jcc=0;jcc<JCHUNKS;++jcc) {
    const float* pp = part + ((size_t)jcc*BN_ + pt)*6;
    #pragma unroll
    for (int k=0;k<6;++k) s[k] += pp[k];
  }
  float acc = log1pf(s[0]) + log1pf(s[1]) + log1pf(s[2])
            + log1pf(s[3]) + log1pf(s[4]) + log1pf(s[5]);
  #pragma unroll
  for (int d=32; d; d>>=1) acc += __shfl_xor(acc, d);
  __shared__ float wsum[4];
  if ((threadIdx.x&63)==0) wsum[threadIdx.x>>6] = acc;
  __syncthreads();
  if (threadIdx.x==0) partial[blockIdx.x] = wsum[0]+wsum[1]+wsum[2]+wsum[3];
}

extern "C" __global__ void fin2_k(const float* __restrict__ partial, float* __restrict__ out)
{
  float acc = partial[threadIdx.x];   // 64 threads
  #pragma unroll
  for (int d=32; d; d>>=1) acc += __shfl_xor(acc, d);
  if (threadIdx.x==0) out[0] = -acc * (1.0f/(float)BN_);
}

extern "C" void kernel_launch(void* const* d_in, const int* in_sizes, int n_in,
                              void* d_out, int out_size, void* d_ws, size_t ws_size,
                              hipStream_t stream)
{
  const float* flow  = (const float*)d_in[0];
  const float* color = (const float*)d_in[1];
  const float* coord = (const float*)d_in[2];
  const float* feat  = (const float*)d_in[3];
  unsigned short* fn = (unsigned short*)d_ws;                                   // 2 MB
  float* scal = (float*)((char*)d_ws + (size_t)BN_*64*2);                       // 768 KB
  float* part = (float*)((char*)d_ws + (size_t)BN_*64*2 + (size_t)BN_*12*4);    // 1.5 MB
  float* partial = part + (size_t)BN_*JCHUNKS*6;                                // 256 B
  float* outp = (float*)d_out;
  hipLaunchKernelGGL(prep_k, dim3(BN_/4), dim3(256), 0, stream,
                     flow, color, coord, feat, fn, scal);
  hipLaunchKernelGGL(main_k, dim3(B_*(N_/64)*JCHUNKS), dim3(256), 0, stream,
                     fn, scal, part);
  hipLaunchKernelGGL(fin1_k, dim3(BN_/256), dim3(256), 0, stream, part, partial);
  hipLaunchKernelGGL(fin2_k, dim3(1), dim3(64), 0, stream, partial, outp);
}